// Round 22
// baseline (453.465 us; speedup 1.0000x reference)
//
#include <hip/hip_runtime.h>
#include <hip/hip_bf16.h>
#include <math.h>

// ---------------------------------------------------------------------------
// GPT2 attention block: out = Attn(h) for B=4, S=2048, H=2048, nh=16, hd=128
// Pipeline (all bf16 MFMA, fp32 accumulate):
//   1) cvt fp32->bf16 (single fused launch, 8 elems/thread)
//   2) gemm_qkv: 256^2-tile, BK=64, m201-style 8-phase window schedule:
//      1 slice staged/phase, vmcnt(8) at even phases ONLY (never drains
//      below 8 in main loop), double barrier per phase. LDS-repack epilogue.
//   3) attn: causal flash attn, KVBLK=64, K-dbuf prefetch, V issue-early,
//      paired q-tiles (qt, 15-qt) per block -> perfect load balance
//   4) gemm_out: same GEMM core; LDS-repack float4 epilogue
// ---------------------------------------------------------------------------

using bf16x8 = __attribute__((ext_vector_type(8))) __bf16;
using f32x4  = __attribute__((ext_vector_type(4))) float;
using s16x8  = __attribute__((ext_vector_type(8))) short;

#define MFMA16(a, b, c) __builtin_amdgcn_mfma_f32_16x16x32_bf16((a), (b), (c), 0, 0, 0)

__device__ __forceinline__ unsigned short f2bf(float f) {
  unsigned u = __float_as_uint(f);
  u += 0x7FFFu + ((u >> 16) & 1u);   // round-to-nearest-even (finite inputs only)
  return (unsigned short)(u >> 16);
}

__device__ __forceinline__ void gload16(const void* g, void* l) {
  __builtin_amdgcn_global_load_lds((const __attribute__((address_space(1))) void*)g,
                                   (__attribute__((address_space(3))) void*)l,
                                   16, 0, 0);
}

// ---------------------------------------------------------------------------
// fused fp32 -> bf16 convert, 8 elems/thread. Grid 16384 x 256.
// ---------------------------------------------------------------------------
__global__ void cvt_all(const float* __restrict__ h,
                        const float* __restrict__ Wq, const float* __restrict__ Wk,
                        const float* __restrict__ Wv, const float* __restrict__ Wo,
                        unsigned short* __restrict__ h_bf,
                        unsigned short* __restrict__ dqkv,
                        unsigned short* __restrict__ dwo) {
  int i = blockIdx.x * 256 + threadIdx.x;
  const float* s; unsigned short* d; int j;
  if (i < 2097152) {
    s = h; d = h_bf; j = i;
  } else {
    int w = (i - 2097152) >> 19;
    j = i & 524287;
    s = (w == 0) ? Wq : (w == 1) ? Wk : (w == 2) ? Wv : Wo;
    d = (w < 3) ? dqkv + w * 4194304 : dwo;
  }
  float4 v0 = ((const float4*)s)[2 * j];
  float4 v1 = ((const float4*)s)[2 * j + 1];
  s16x8 o;
  o[0] = (short)f2bf(v0.x); o[1] = (short)f2bf(v0.y);
  o[2] = (short)f2bf(v0.z); o[3] = (short)f2bf(v0.w);
  o[4] = (short)f2bf(v1.x); o[5] = (short)f2bf(v1.y);
  o[6] = (short)f2bf(v1.z); o[7] = (short)f2bf(v1.w);
  ((s16x8*)d)[j] = o;
}

// ---------------------------------------------------------------------------
// 256x256-tile, BK=64, 8-wave (2Mx4N) GEMM core — m201 8-phase schedule.
// LDS: lA/lB[2 dbuf][2 khalf][256 rows x 32 k] = 128 KiB.
// Window u = tiles {2u (dbuf0), 2u+1 (dbuf1)}, 8 phases (D,KK,MH):
//   ph(D,KK,mh0): 4 A + 4 B ds_read; ph(D,KK,mh1): 4 A (B held in regs).
// Slice death: B[d][kk] after its mh0 phase; A[d][kk] after its mh1 phase.
// Stage exactly 1 slice/phase, one phase AFTER its death (race-free by the
// double-barrier-per-phase discipline; stage issues after the barrier that
// closes the slice's last reading phase):
//   ph1: A[1][1]<-t+1 | ph2: B[0][0]<-t+2 | ph3: A[0][0] | ph4: B[0][1]
//   ph5: A[0][1]      | ph6: B[1][0]<-t+3 | ph7: A[1][0] | ph8: B[1][1]
// Waits: VMC(8) at even phases only (FIFO audit: queue=12 loads, retires
// exactly the 2 slices read in the next 2 phases; never below 8 in flight;
// 6-7 phase prefetch lead >= HBM latency). Prologue: 7 slices + VMC(8).
// Tail window: ph1 stage only; waits 8/4/0/0 (audited).
// Swizzle g(r)=(r>>1)&3 on 16B slots, both-sides (verified 0 conflicts).
// ---------------------------------------------------------------------------

#define GEMM_PRE()                                                             \
  const int tid = threadIdx.x;                                                 \
  const int wave = tid >> 6, lane = tid & 63;                                  \
  const int lo = lane & 15, hi = lane >> 4;                                    \
  const int wr = wave >> 2, wc = wave & 3;                                     \
  const int r4 = lane >> 2, s4 = lane & 3;                                     \
  const int scol = ((s4 ^ ((r4 >> 1) & 3)) << 3);                              \
  const int swz = ((hi ^ ((lo >> 1) & 3)) << 3);                               \
  const unsigned short* aBase[2]; const unsigned short* bBase[2];              \
  _Pragma("unroll")                                                            \
  for (int j = 0; j < 2; ++j) {                                                \
    aBase[j] = A + (size_t)(m0 + (wave * 2 + j) * 16 + r4) * 2048 + scol;      \
    bBase[j] = W + (size_t)(n0 + (wave * 2 + j) * 16 + r4) * 2048 + scol;      \
  }                                                                            \
  f32x4 acc[8][4] = {};

#define STAGEA(D, KK, KOFF)                                                    \
  do {                                                                         \
    gload16(aBase[0] + (KOFF), &lA[D][KK][(wave * 2 + 0) * 512]);              \
    gload16(aBase[1] + (KOFF), &lA[D][KK][(wave * 2 + 1) * 512]);              \
  } while (0)

#define STAGEB(D, KK, KOFF)                                                    \
  do {                                                                         \
    gload16(bBase[0] + (KOFF), &lB[D][KK][(wave * 2 + 0) * 512]);              \
    gload16(bBase[1] + (KOFF), &lB[D][KK][(wave * 2 + 1) * 512]);              \
  } while (0)

#define LDA4W(dst, D, KK, MH)                                                  \
  do {                                                                         \
    _Pragma("unroll")                                                          \
    for (int im = 0; im < 4; ++im)                                             \
      dst[im] = *(const bf16x8*)&lA[D][KK][(wr * 128 + (MH)*64 + im * 16 + lo) * 32 + swz]; \
  } while (0)

#define LDB4W(dst, D, KK)                                                      \
  do {                                                                         \
    _Pragma("unroll")                                                          \
    for (int ni = 0; ni < 4; ++ni)                                             \
      dst[ni] = *(const bf16x8*)&lB[D][KK][(wc * 64 + ni * 16 + lo) * 32 + swz]; \
  } while (0)

#define MFP(MH, aF, bF)                                                        \
  do {                                                                         \
    __builtin_amdgcn_s_setprio(1);                                             \
    _Pragma("unroll")                                                          \
    for (int im = 0; im < 4; ++im)                                             \
      _Pragma("unroll")                                                        \
      for (int ni = 0; ni < 4; ++ni)                                           \
        acc[(MH)*4 + im][ni] = MFMA16(aF[im], bF[ni], acc[(MH)*4 + im][ni]);   \
    __builtin_amdgcn_s_setprio(0);                                             \
  } while (0)

#define BAR __builtin_amdgcn_s_barrier()
#define VMC(N) asm volatile("s_waitcnt vmcnt(" #N ")" ::: "memory")

// one 8-phase window; KB = 128*u (element k-offset of tile 2u)
#define WINDOW(KB, CS, V2, V4, V6, V8)                                         \
  do {                                                                         \
    bf16x8 aF[4], bF[4];                                                       \
    /* ph1: T0 kk0 mh0 | stage A[1][1] (t+1 kh1) */                            \
    LDA4W(aF, 0, 0, 0); LDB4W(bF, 0, 0);                                       \
    STAGEA(1, 1, (KB) + 96);                                                   \
    BAR; MFP(0, aF, bF); BAR;                                                  \
    /* ph2: T0 kk0 mh1 | stage B[0][0] (t+2 kh0) */                            \
    LDA4W(aF, 0, 0, 1);                                                        \
    if (CS) STAGEB(0, 0, (KB) + 128);                                          \
    BAR; MFP(1, aF, bF); VMC(V2); BAR;                                         \
    /* ph3: T0 kk1 mh0 | stage A[0][0] */                                      \
    LDA4W(aF, 0, 1, 0); LDB4W(bF, 0, 1);                                       \
    if (CS) STAGEA(0, 0, (KB) + 128);                                          \
    BAR; MFP(0, aF, bF); BAR;                                                  \
    /* ph4: T0 kk1 mh1 | stage B[0][1] */                                      \
    LDA4W(aF, 0, 1, 1);                                                        \
    if (CS) STAGEB(0, 1, (KB) + 160);                                          \
    BAR; MFP(1, aF, bF); VMC(V4); BAR;                                         \
    /* ph5: T1 kk0 mh0 | stage A[0][1] */                                      \
    LDA4W(aF, 1, 0, 0); LDB4W(bF, 1, 0);                                       \
    if (CS) STAGEA(0, 1, (KB) + 160);                                          \
    BAR; MFP(0, aF, bF); BAR;                                                  \
    /* ph6: T1 kk0 mh1 | stage B[1][0] (t+3 kh0) */                            \
    LDA4W(aF, 1, 0, 1);                                                        \
    if (CS) STAGEB(1, 0, (KB) + 192);                                          \
    BAR; MFP(1, aF, bF); VMC(V6); BAR;                                         \
    /* ph7: T1 kk1 mh0 | stage A[1][0] */                                      \
    LDA4W(aF, 1, 1, 0); LDB4W(bF, 1, 1);                                       \
    if (CS) STAGEA(1, 0, (KB) + 192);                                          \
    BAR; MFP(0, aF, bF); BAR;                                                  \
    /* ph8: T1 kk1 mh1 | stage B[1][1] */                                      \
    LDA4W(aF, 1, 1, 1);                                                        \
    if (CS) STAGEB(1, 1, (KB) + 224);                                          \
    BAR; MFP(1, aF, bF); VMC(V8); BAR;                                         \
  } while (0)

#define GEMM_MAIN()                                                            \
  /* prologue: 7 slices in steady FIFO order, retire first 3 */               \
  STAGEB(0, 0, 0);  STAGEA(0, 0, 0);                                           \
  STAGEB(0, 1, 32); STAGEA(0, 1, 32);                                          \
  STAGEB(1, 0, 64); STAGEA(1, 0, 64);                                          \
  STAGEB(1, 1, 96);                                                            \
  VMC(8); BAR;                                                                 \
  for (int u = 0; u < 15; ++u) {                                               \
    const int kb = u * 128;                                                    \
    WINDOW(kb, true, 8, 8, 8, 8);                                              \
  }                                                                            \
  WINDOW(1920, false, 8, 4, 0, 0);

// ---------------------------------------------------------------------------
// QKV GEMM: M=8192 (B*S), N=6144 (Wq;Wk;Wv), K=2048. Output scattered into
// Q/K/V [b,nh,S,hd] bf16 with bias. LDS-repack epilogue (16B-line stores).
// ---------------------------------------------------------------------------
__global__ __launch_bounds__(512, 2)
void gemm_qkv(const unsigned short* __restrict__ A,
              const unsigned short* __restrict__ W,
              const float* __restrict__ bq, const float* __restrict__ bk,
              const float* __restrict__ bv,
              unsigned short* __restrict__ Q, unsigned short* __restrict__ Kq,
              unsigned short* __restrict__ V) {
  __shared__ unsigned short lA[2][2][256 * 32];
  __shared__ unsigned short lB[2][2][256 * 32];
  const int bid = blockIdx.x;
  const int sid = (bid & 7) * 96 + (bid >> 3);
  const int bm = sid / 24, bn = sid % 24;
  const int m0 = bm * 256, n0 = bn * 256;
  GEMM_PRE();
  GEMM_MAIN();

  const int which = n0 >> 11;
  const float* bias = (which == 0) ? bq : (which == 1) ? bk : bv;
  unsigned short* dst = (which == 0) ? Q : (which == 1) ? Kq : V;

  // wave-private patch: 64 rows x 72 ushorts (9216 B, 16B-aligned rows)
  unsigned short* patch = (wave < 4) ? (&lA[0][0][0] + wave * 4608)
                                     : (&lB[0][0][0] + (wave - 4) * 4608);
  const int nbase = n0 + wc * 64;            // 64-col span, single head
  const int head = (nbase & 2047) >> 7;
  const int d0 = nbase & 127;                // 0 or 64
#pragma unroll
  for (int pass = 0; pass < 2; ++pass) {
    asm volatile("s_waitcnt lgkmcnt(0)" ::: "memory");  // WAR vs prior pass reads
#pragma unroll
    for (int mi = 0; mi < 4; ++mi)
#pragma unroll
      for (int ni = 0; ni < 4; ++ni) {
        int n2 = (nbase + ni * 16 + lo) & 2047;
        float bb = bias[n2];
#pragma unroll
        for (int i = 0; i < 4; ++i)
          patch[(mi * 16 + hi * 4 + i) * 72 + ni * 16 + lo] =
              f2bf(acc[pass * 4 + mi][ni][i] + bb);
      }
    asm volatile("s_waitcnt lgkmcnt(0)" ::: "memory");  // writes visible to reads
#pragma unroll
    for (int it = 0; it < 8; ++it) {
      int rl = it * 8 + (lane >> 3);
      int coff = (lane & 7) * 8;
      s16x8 v = *(const s16x8*)&patch[rl * 72 + coff];
      int m = m0 + wr * 128 + pass * 64 + rl;
      int b = m >> 11, s = m & 2047;
      *(s16x8*)&dst[(((size_t)b * 16 + head) * 2048 + s) * 128 + d0 + coff] = v;
    }
  }
}

// ---------------------------------------------------------------------------
// Output GEMM: M=8192, N=2048, K=2048, fp32 out + bias.
// LDS-repack epilogue: fp32 patch 32 rows x 68 floats, float4 stores.
// ---------------------------------------------------------------------------
__global__ __launch_bounds__(512, 2)
void gemm_out(const unsigned short* __restrict__ A,
              const unsigned short* __restrict__ W,
              const float* __restrict__ bo, float* __restrict__ out) {
  __shared__ unsigned short lA[2][2][256 * 32];
  __shared__ unsigned short lB[2][2][256 * 32];
  const int bid = blockIdx.x;
  const int sid = (bid & 7) * 32 + (bid >> 3);
  const int bm = sid >> 3, bn = sid & 7;
  const int m0 = bm * 256, n0 = bn * 256;
  GEMM_PRE();
  GEMM_MAIN();

  // wave-private fp32 patch: 32 x 68 floats = 8704 B (16B-aligned rows)
  float* patch = (float*)((wave < 4) ? (&lA[0][0][0] + wave * 4352)
                                     : (&lB[0][0][0] + (wave - 4) * 4352));
  const int nbase = n0 + wc * 64;
#pragma unroll
  for (int pass = 0; pass < 4; ++pass) {
    asm volatile("s_waitcnt lgkmcnt(0)" ::: "memory");  // WAR vs prior pass reads
#pragma unroll
    for (int mi = 0; mi < 2; ++mi)
#pragma unroll
      for (int ni = 0; ni < 4; ++ni) {
        float bb = bo[nbase + ni * 16 + lo];
#pragma unroll
        for (int i = 0; i < 4; ++i)
          patch[(mi * 16 + hi * 4 + i) * 68 + ni * 16 + lo] =
              acc[pass * 2 + mi][ni][i] + bb;
      }
    asm volatile("s_waitcnt lgkmcnt(0)" ::: "memory");  // writes visible to reads
#pragma unroll
    for (int it = 0; it < 8; ++it) {
      int rl = it * 4 + hi;
      int coff = lo * 4;
      float4 v = *(const float4*)&patch[rl * 68 + coff];
      int m = m0 + wr * 128 + pass * 32 + rl;
      *(float4*)&out[(size_t)m * 2048 + nbase + coff] = v;
    }
  }
}

// ---------------------------------------------------------------------------
// Causal flash attention, KVBLK=64, K double-buffered with counted-vmcnt
// prefetch; V issue-early/write-late (T14); setprio on MFMA clusters (T5).
// PAIRED q-tiles: block (bh, pr) handles qt = 15-pr then qt = pr -> every
// block does exactly 34 tile-units; grid 512 = 2 blocks/CU, all resident.
// Softmax: log2 domain, defer-max (T13); l via ones-column MFMA (acc[*][8]).
// ---------------------------------------------------------------------------
__global__ __launch_bounds__(256, 2)
void attn_kernel(const unsigned short* __restrict__ Qb,
                 const unsigned short* __restrict__ Kb,
                 const unsigned short* __restrict__ Vb,
                 unsigned short* __restrict__ Ob) {
  __shared__ unsigned short lK[2][64 * 128];    // 2 x 16 KB, swizzled rows
  __shared__ unsigned short lVt[144 * 72];      // V^T + ones rows 128..143
  __shared__ unsigned short lP[4][32 * 72];     // per-wave P [32 q][64 k]

  const int tid = threadIdx.x;
  const int wave = tid >> 6, lane = tid & 63;
  const int lo = lane & 15, hi = lane >> 4;
  const int bh = blockIdx.x & 63;
  const int pr = blockIdx.x >> 6;               // 0..7 (q-tile pair index)
  const size_t base = (size_t)bh * 2048 * 128;
  const float SCL = 0.08838834764831845f * 1.4426950408889634f;
  const float THR = 11.5416f;                   // 8 * log2(e)
  const int rr = tid & 31, c0v = (tid >> 5) * 8;

  // ones rows (d=128..143, 64 cols); written once, never overwritten
#pragma unroll
  for (int x = tid; x < 1024; x += 256)
    lVt[(128 + (x >> 6)) * 72 + (x & 63)] = 0x3F80;  // bf16 1.0

#define STAGEK(KT2, BUF)                                                       \
  do {                                                                         \
    _Pragma("unroll")                                                          \
    for (int j = 0; j < 4; j++) {                                              \
      int lrow = j * 16 + wave * 4 + hi;                                       \
      int srccol = (lo * 16) ^ ((lrow & 7) << 4);                              \
      gload16(Kb + base + (size_t)((KT2) * 64 + lrow) * 128 + (srccol >> 1),   \
              &lK[BUF][(j * 16 + wave * 4) * 128]);                            \
    }                                                                          \
  } while (0)

  for (int hseq = 0; hseq < 2; ++hseq) {
    const int qt = hseq ? pr : 15 - pr;         // heavy subtile first
    const int q0 = qt * 128 + wave * 32;
    const int ktn = qt * 2 + 2;                 // 64-key tiles to causal edge
    const int qmax_w = q0 + 31;

    bf16x8 aq[2][4];
#pragma unroll
    for (int mi = 0; mi < 2; mi++)
#pragma unroll
      for (int dk = 0; dk < 4; dk++)
        aq[mi][dk] = *(const bf16x8*)&Qb[base + (size_t)(q0 + mi * 16 + lo) * 128 + dk * 32 + hi * 8];

    f32x4 acc[2][9] = {};                       // [.][8] = l (ones column)
    float mrun[2][4];
#pragma unroll
    for (int a = 0; a < 2; a++)
#pragma unroll
      for (int b = 0; b < 4; b++) mrun[a][b] = -INFINITY;

    STAGEK(0, 0);

    for (int kt = 0; kt < ktn; kt++) {
      // ---- V issue-early (4 global loads to regs; oldest in vmcnt queue) ----
      const unsigned short* vp0 = Vb + base + (size_t)(kt * 64 + 2 * rr) * 128 + c0v;
      s16x8 v00 = *(const s16x8*)vp0;
      s16x8 v01 = *(const s16x8*)(vp0 + 128);
      s16x8 v10 = *(const s16x8*)(vp0 + 64);
      s16x8 v11 = *(const s16x8*)(vp0 + 192);
      // ---- K(kt+1) prefetch; drain K(kt)+V only ----
      if (kt + 1 < ktn) { STAGEK(kt + 1, (kt + 1) & 1); VMC(8); }
      else { VMC(0); }
      BAR;

      const bool docomp = (kt * 64 <= qmax_w);
      if (docomp) {
        const unsigned short* lKc = &lK[kt & 1][0];
        f32x4 sc[2][4] = {};
        __builtin_amdgcn_s_setprio(1);
#pragma unroll
        for (int ni = 0; ni < 4; ni++)
#pragma unroll
          for (int dk = 0; dk < 4; dk++) {
            int row = ni * 16 + lo;
            int col = (dk * 32 + hi * 8) ^ ((row & 7) << 3);
            bf16x8 bk_ = *(const bf16x8*)&lKc[row * 128 + col];
            sc[0][ni] = MFMA16(aq[0][dk], bk_, sc[0][ni]);
            sc[1][ni] = MFMA16(aq[1][dk], bk_, sc[1][ni]);
          }
        __builtin_amdgcn_s_setprio(0);
        float tm[2][4];
        bool cond = true;
#pragma unroll
        for (int mi = 0; mi < 2; mi++)
#pragma unroll
          for (int i = 0; i < 4; i++) {
            int qrow = q0 + mi * 16 + hi * 4 + i;
            float mx = -INFINITY;
#pragma unroll
            for (int ni = 0; ni < 4; ni++) {
              int kc = kt * 64 + ni * 16 + lo;
              float s = sc[mi][ni][i] * SCL;
              if (kc > qrow) s = -INFINITY;
              sc[mi][ni][i] = s;
              mx = fmaxf(mx, s);
            }
            tm[mi][i] = mx;
            cond = cond && (mx <= mrun[mi][i] + THR);
          }
        if (!__all((int)cond)) {
#pragma unroll
          for (int mi = 0; mi < 2; mi++)
#pragma unroll
            for (int i = 0; i < 4; i++) {
              float mt = tm[mi][i];
              mt = fmaxf(mt, __shfl_xor(mt, 1));
              mt = fmaxf(mt, __shfl_xor(mt, 2));
              mt = fmaxf(mt, __shfl_xor(mt, 4));
              mt = fmaxf(mt, __shfl_xor(mt, 8));
              float mo = mrun[mi][i];
              float mn = fmaxf(mo, mt);
              float alpha = exp2f(mo - mn);
              mrun[mi][i] = mn;
#pragma unroll
              for (int ni = 0; ni < 9; ni++) acc[mi][ni][i] *= alpha;
            }
        }
        unsigned short* lPw = &lP[wave][0];
#pragma unroll
        for (int mi = 0; mi < 2; mi++)
#pragma unroll
          for (int i = 0; i < 4; i++) {
            float m = mrun[mi][i];
            int prow = mi * 16 + hi * 4 + i;
#pragma unroll
            for (int ni = 0; ni < 4; ni++)
              lPw[prow * 72 + ni * 16 + lo] = f2bf(exp2f(sc[mi][ni][i] - m));
          }
      }

      // ---- V write-late (compiler-inserted waits cover the V regs) ----
#pragma unroll
      for (int j = 0; j < 8; j++) {
        *(ushort2*)&lVt[(c0v + j) * 72 + 2 * rr] =
            make_ushort2((unsigned short)v00[j], (unsigned short)v01[j]);
        *(ushort2*)&lVt[(c0v + 64 + j) * 72 + 2 * rr] =
            make_ushort2((unsigned short)v10[j], (unsigned short)v11[j]);
      }
      asm volatile("s_waitcnt lgkmcnt(0)" ::: "memory");
      BAR;

      if (docomp) {
        unsigned short* lPw = &lP[wave][0];
        bf16x8 ap[2][2];
#pragma unroll
        for (int mi = 0; mi < 2; mi++)
#pragma unroll
          for (int k2 = 0; k2 < 2; k2++)
            ap[mi][k2] = *(const bf16x8*)&lPw[(mi * 16 + lo) * 72 + k2 * 32 + hi * 8];
        __builtin_amdgcn_s_setprio(1);
#pragma unroll
        for (int ni = 0; ni < 9; ni++)
#pragma unroll
          for (int k2 = 0; k2 < 2; k2++) {
            bf16x8 bv_ = *(const bf16x8*)&lVt[(ni * 16 + lo) * 72 + k2 * 32 + hi * 8];
            acc[0][ni] = MFMA16(ap[0][k2], bv_, acc[0][ni]);
            acc[1][ni] = MFMA16(ap[1][k2], bv_, acc[1][ni]);
          }
        __builtin_amdgcn_s_setprio(0);
      }
    }

    // ---- epilogue: O[b, s, h*128+d] = acc / l, l = acc[mi][8][i] ----
    const int b = bh >> 4, hh = bh & 15;
#pragma unroll
    for (int mi = 0; mi < 2; mi++)
#pragma unroll
      for (int i = 0; i < 4; i++) {
        float inv = 1.0f / acc[mi][8][i];
        int s = q0 + mi * 16 + hi * 4 + i;
        size_t rowbase = ((size_t)b * 2048 + s) * 2048 + hh * 128 + lo;
#pragma unroll
        for (int ni = 0; ni < 8; ni++)
          Ob[rowbase + ni * 16] = f2bf(acc[mi][ni][i] * inv);
      }
  }
}

// ---------------------------------------------------------------------------
extern "C" void kernel_launch(void* const* d_in, const int* in_sizes, int n_in,
                              void* d_out, int out_size, void* d_ws, size_t ws_size,
                              hipStream_t stream) {
  const float* h  = (const float*)d_in[0];
  const float* Wq = (const float*)d_in[1];
  const float* bq = (const float*)d_in[2];
  const float* Wk = (const float*)d_in[3];
  const float* bk = (const float*)d_in[4];
  const float* Wv = (const float*)d_in[5];
  const float* bv = (const float*)d_in[6];
  const float* Wo = (const float*)d_in[7];
  const float* bo = (const float*)d_in[8];
  float* out = (float*)d_out;

  char* ws = (char*)d_ws;
  unsigned short* h_bf  = (unsigned short*)(ws + 0);            // 32 MiB
  unsigned short* Qb    = (unsigned short*)(ws + 33554432);     // 32 MiB
  unsigned short* Kb    = (unsigned short*)(ws + 67108864);     // 32 MiB
  unsigned short* Vb    = (unsigned short*)(ws + 100663296);    // 32 MiB
  unsigned short* Wqkv  = (unsigned short*)(ws + 134217728);    // 24 MiB
  unsigned short* Wo_bf = (unsigned short*)(ws + 159383552);    // 8 MiB
  unsigned short* Ob    = h_bf;                                 // reuse after QKV GEMM

  // fp32 -> bf16 conversions (h + all weights, one launch)
  cvt_all<<<16384, 256, 0, stream>>>(h, Wq, Wk, Wv, Wo, h_bf, Wqkv, Wo_bf);

  // QKV projection (M=8192, N=6144, K=2048), 32x24 blocks of 256x256
  gemm_qkv<<<dim3(768), dim3(512), 0, stream>>>(h_bf, Wqkv, bq, bk, bv, Qb, Kb, Vb);

  // causal attention (64 bh x 8 q-tile pairs)
  attn_kernel<<<dim3(512), dim3(256), 0, stream>>>(Qb, Kb, Vb, Ob);

  // output projection (M=8192, N=2048, K=2048), 32x8 blocks, fp32 out
  gemm_out<<<dim3(256), dim3(512), 0, stream>>>(Ob, Wo_bf, bo, out);
}

// Round 23
// 419.013 us; speedup vs baseline: 1.0822x; 1.0822x over previous
//
#include <hip/hip_runtime.h>
#include <hip/hip_bf16.h>
#include <math.h>

// ---------------------------------------------------------------------------
// GPT2 attention block: out = Attn(h) for B=4, S=2048, H=2048, nh=16, hd=128
// FINAL CONFIG (round-19/21 optimum, 420-421 us, reproduced 3x).
// Six GEMM schedule restructures (incl. two m201-style 8-phase ports) all
// regressed vs this core; occupancy vs reuse resolved in favor of reuse 2x.
// Pipeline (all bf16 MFMA, fp32 accumulate):
//   1) cvt fp32->bf16 (single fused launch, 8 elems/thread, 16B stores)
//   2) gemm_qkv: 256^2-tile GEMM (BK=32, 4-buf, stage-ahead-3, vmcnt(8)),
//      ONE barrier per K-tile; LDS-repack epilogue (16B stores)
//   3) attn: causal flash attn, KVBLK=64, K-dbuf prefetch, V issue-early,
//      paired q-tiles (qt, 15-qt) per block -> perfect load balance
//   4) gemm_out: same GEMM core; LDS-repack epilogue (float4 stores)
// ---------------------------------------------------------------------------

using bf16x8 = __attribute__((ext_vector_type(8))) __bf16;
using f32x4  = __attribute__((ext_vector_type(4))) float;
using s16x8  = __attribute__((ext_vector_type(8))) short;

#define MFMA16(a, b, c) __builtin_amdgcn_mfma_f32_16x16x32_bf16((a), (b), (c), 0, 0, 0)

__device__ __forceinline__ unsigned short f2bf(float f) {
  unsigned u = __float_as_uint(f);
  u += 0x7FFFu + ((u >> 16) & 1u);   // round-to-nearest-even (finite inputs only)
  return (unsigned short)(u >> 16);
}

__device__ __forceinline__ void gload16(const void* g, void* l) {
  __builtin_amdgcn_global_load_lds((const __attribute__((address_space(1))) void*)g,
                                   (__attribute__((address_space(3))) void*)l,
                                   16, 0, 0);
}

// ---------------------------------------------------------------------------
// fused fp32 -> bf16 convert, 8 elems/thread (2x float4 read, 1x 16B store):
// h (2M units), then Wq,Wk,Wv->Wqkv, Wo->Wo_bf (512K units each). 16384x256.
// ---------------------------------------------------------------------------
__global__ void cvt_all(const float* __restrict__ h,
                        const float* __restrict__ Wq, const float* __restrict__ Wk,
                        const float* __restrict__ Wv, const float* __restrict__ Wo,
                        unsigned short* __restrict__ h_bf,
                        unsigned short* __restrict__ dqkv,
                        unsigned short* __restrict__ dwo) {
  int i = blockIdx.x * 256 + threadIdx.x;
  const float* s; unsigned short* d; int j;
  if (i < 2097152) {
    s = h; d = h_bf; j = i;
  } else {
    int w = (i - 2097152) >> 19;
    j = i & 524287;
    s = (w == 0) ? Wq : (w == 1) ? Wk : (w == 2) ? Wv : Wo;
    d = (w < 3) ? dqkv + w * 4194304 : dwo;
  }
  float4 v0 = ((const float4*)s)[2 * j];
  float4 v1 = ((const float4*)s)[2 * j + 1];
  s16x8 o;
  o[0] = (short)f2bf(v0.x); o[1] = (short)f2bf(v0.y);
  o[2] = (short)f2bf(v0.z); o[3] = (short)f2bf(v0.w);
  o[4] = (short)f2bf(v1.x); o[5] = (short)f2bf(v1.y);
  o[6] = (short)f2bf(v1.z); o[7] = (short)f2bf(v1.w);
  ((s16x8*)d)[j] = o;
}

// ---------------------------------------------------------------------------
// 256x256-tile, BK=32, 8-wave (2Mx4N) GEMM core, counted-vmcnt pipeline,
// ONE barrier per K-tile. (measured best: ~192 us qkv, MfmaUtil ~48%)
// LDS: 4 buffers x (A[256][32] + B[256][32]) bf16 = 128 KiB. Tile t reads
// buf t%4, stages tile t+3 into (t+3)%4; VMC(8) at tile end (waits loads
// issued 3 tiles ago -> near-free); tail 8/4/0/0.
// Swizzle g(r)=(r>>1)&3 on 16B slots, both-sides (verified ~0 conflicts).
// Publish-granularity audit: with 32KB/K-slice buffers and 160KB LDS, >=1
// vmcnt+barrier publish per 32-K tile is structurally required — this core
// is at that bound.
// ---------------------------------------------------------------------------

#define GEMM_PRE()                                                             \
  const int tid = threadIdx.x;                                                 \
  const int wave = tid >> 6, lane = tid & 63;                                  \
  const int lo = lane & 15, hi = lane >> 4;                                    \
  const int wr = wave >> 2, wc = wave & 3;                                     \
  const int r4 = lane >> 2, s4 = lane & 3;                                     \
  const int scol = ((s4 ^ ((r4 >> 1) & 3)) << 3);                              \
  const unsigned short* aS[2]; const unsigned short* bS[2];                    \
  _Pragma("unroll")                                                            \
  for (int j = 0; j < 2; ++j) {                                                \
    aS[j] = A + (size_t)(m0 + (wave * 2 + j) * 16 + r4) * 2048 + scol;         \
    bS[j] = W + (size_t)(n0 + (wave * 2 + j) * 16 + r4) * 2048 + scol;         \
  }                                                                            \
  f32x4 acc[8][4] = {};

#define STAGE2(BUF, J)                                                         \
  do {                                                                         \
    gload16(aS[J], &lA[BUF][(wave * 2 + (J)) * 512]);                          \
    gload16(bS[J], &lB[BUF][(wave * 2 + (J)) * 512]);                          \
    aS[J] += 32; bS[J] += 32;                                                  \
  } while (0)

#define LDA4_(dst, MH, BUF)                                                    \
  do {                                                                         \
    _Pragma("unroll")                                                          \
    for (int im = 0; im < 4; ++im)                                             \
      dst[im] = *(const bf16x8*)&lA[BUF][(wr * 128 + (MH)*64 + im * 16 + lo) * 32 + \
                                         ((hi ^ ((lo >> 1) & 3)) << 3)];       \
  } while (0)

#define LDB4_(dst, BUF)                                                        \
  do {                                                                         \
    _Pragma("unroll")                                                          \
    for (int ni = 0; ni < 4; ++ni)                                             \
      dst[ni] = *(const bf16x8*)&lB[BUF][(wc * 64 + ni * 16 + lo) * 32 +       \
                                         ((hi ^ ((lo >> 1) & 3)) << 3)];       \
  } while (0)

// MFMA half-cluster without setprio (caller wraps the full 32-MFMA cluster)
#define MF16NP(MH, aF, bF)                                                     \
  do {                                                                         \
    _Pragma("unroll")                                                          \
    for (int im = 0; im < 4; ++im)                                             \
      _Pragma("unroll")                                                        \
      for (int ni = 0; ni < 4; ++ni)                                           \
        acc[(MH)*4 + im][ni] = MFMA16(aF[im], bF[ni], acc[(MH)*4 + im][ni]);   \
  } while (0)

#define BAR __builtin_amdgcn_s_barrier()
#define VMC(N) asm volatile("s_waitcnt vmcnt(" #N ")" ::: "memory")

// one K-tile, ONE barrier: reads+stages up front, 32 MFMA, counted wait, BAR
#define TILE(RBUF, SBUF, COND, VN)                                             \
  do {                                                                         \
    bf16x8 aF[4], aG[4], bF[4];                                                \
    LDA4_(aF, 0, RBUF); LDB4_(bF, RBUF); LDA4_(aG, 1, RBUF);                   \
    if (COND) { STAGE2(SBUF, 0); STAGE2(SBUF, 1); }                            \
    __builtin_amdgcn_s_setprio(1);                                             \
    MF16NP(0, aF, bF);                                                         \
    MF16NP(1, aG, bF);                                                         \
    __builtin_amdgcn_s_setprio(0);                                             \
    VMC(VN); BAR;                                                              \
  } while (0)

#define GEMM_MAIN()                                                            \
  STAGE2(0, 0); STAGE2(0, 1); STAGE2(1, 0); STAGE2(1, 1);                      \
  STAGE2(2, 0); STAGE2(2, 1);                                                  \
  VMC(8); BAR;                                                                 \
  for (int u = 0; u < 15; ++u) {                                               \
    TILE(0, 3, true, 8); TILE(1, 0, true, 8);                                  \
    TILE(2, 1, true, 8); TILE(3, 2, true, 8);                                  \
  }                                                                            \
  TILE(0, 3, true, 8); TILE(1, 0, false, 4);                                   \
  TILE(2, 1, false, 0); TILE(3, 2, false, 0);

// ---------------------------------------------------------------------------
// QKV GEMM: M=8192 (B*S), N=6144 (Wq;Wk;Wv), K=2048. Output scattered into
// Q/K/V [b,nh,S,hd] bf16 with bias. LDS-repack epilogue (16B-line stores).
// ---------------------------------------------------------------------------
__global__ __launch_bounds__(512, 2)
void gemm_qkv(const unsigned short* __restrict__ A,
              const unsigned short* __restrict__ W,
              const float* __restrict__ bq, const float* __restrict__ bk,
              const float* __restrict__ bv,
              unsigned short* __restrict__ Q, unsigned short* __restrict__ Kq,
              unsigned short* __restrict__ V) {
  __shared__ unsigned short lA[4][256 * 32];
  __shared__ unsigned short lB[4][256 * 32];
  const int bid = blockIdx.x;
  const int sid = (bid & 7) * 96 + (bid >> 3);
  const int bm = sid / 24, bn = sid % 24;
  const int m0 = bm * 256, n0 = bn * 256;
  GEMM_PRE();
  GEMM_MAIN();

  const int which = n0 >> 11;
  const float* bias = (which == 0) ? bq : (which == 1) ? bk : bv;
  unsigned short* dst = (which == 0) ? Q : (which == 1) ? Kq : V;

  // wave-private patch: 64 rows x 72 ushorts (9216 B, 16B-aligned rows)
  unsigned short* patch = (wave < 4) ? (&lA[0][0] + wave * 4608)
                                     : (&lB[0][0] + (wave - 4) * 4608);
  const int nbase = n0 + wc * 64;            // 64-col span, single head
  const int head = (nbase & 2047) >> 7;
  const int d0 = nbase & 127;                // 0 or 64
#pragma unroll
  for (int pass = 0; pass < 2; ++pass) {
    asm volatile("s_waitcnt lgkmcnt(0)" ::: "memory");  // WAR vs prior pass reads
#pragma unroll
    for (int mi = 0; mi < 4; ++mi)
#pragma unroll
      for (int ni = 0; ni < 4; ++ni) {
        int n2 = (nbase + ni * 16 + lo) & 2047;
        float bb = bias[n2];
#pragma unroll
        for (int i = 0; i < 4; ++i)
          patch[(mi * 16 + hi * 4 + i) * 72 + ni * 16 + lo] =
              f2bf(acc[pass * 4 + mi][ni][i] + bb);
      }
    asm volatile("s_waitcnt lgkmcnt(0)" ::: "memory");  // writes visible to reads
#pragma unroll
    for (int it = 0; it < 8; ++it) {
      int rl = it * 8 + (lane >> 3);
      int coff = (lane & 7) * 8;
      s16x8 v = *(const s16x8*)&patch[rl * 72 + coff];
      int m = m0 + wr * 128 + pass * 64 + rl;
      int b = m >> 11, s = m & 2047;
      *(s16x8*)&dst[(((size_t)b * 16 + head) * 2048 + s) * 128 + d0 + coff] = v;
    }
  }
}

// ---------------------------------------------------------------------------
// Output GEMM: M=8192, N=2048, K=2048, fp32 out + bias.
// LDS-repack epilogue: fp32 patch 32 rows x 68 floats (16B-aligned rows),
// 4 passes, float4 full-line stores.
// ---------------------------------------------------------------------------
__global__ __launch_bounds__(512, 2)
void gemm_out(const unsigned short* __restrict__ A,
              const unsigned short* __restrict__ W,
              const float* __restrict__ bo, float* __restrict__ out) {
  __shared__ unsigned short lA[4][256 * 32];
  __shared__ unsigned short lB[4][256 * 32];
  const int bid = blockIdx.x;
  const int sid = (bid & 7) * 32 + (bid >> 3);
  const int bm = sid >> 3, bn = sid & 7;
  const int m0 = bm * 256, n0 = bn * 256;
  GEMM_PRE();
  GEMM_MAIN();

  // wave-private fp32 patch: 32 x 68 floats = 8704 B (16B-aligned rows)
  float* patch = (float*)((wave < 4) ? (&lA[0][0] + wave * 4352)
                                     : (&lB[0][0] + (wave - 4) * 4352));
  const int nbase = n0 + wc * 64;
#pragma unroll
  for (int pass = 0; pass < 4; ++pass) {
    asm volatile("s_waitcnt lgkmcnt(0)" ::: "memory");  // WAR vs prior pass reads
#pragma unroll
    for (int mi = 0; mi < 2; ++mi)
#pragma unroll
      for (int ni = 0; ni < 4; ++ni) {
        float bb = bo[nbase + ni * 16 + lo];
#pragma unroll
        for (int i = 0; i < 4; ++i)
          patch[(mi * 16 + hi * 4 + i) * 68 + ni * 16 + lo] =
              acc[pass * 2 + mi][ni][i] + bb;
      }
    asm volatile("s_waitcnt lgkmcnt(0)" ::: "memory");  // writes visible to reads
#pragma unroll
    for (int it = 0; it < 8; ++it) {
      int rl = it * 4 + hi;
      int coff = lo * 4;
      float4 v = *(const float4*)&patch[rl * 68 + coff];
      int m = m0 + wr * 128 + pass * 32 + rl;
      *(float4*)&out[(size_t)m * 2048 + nbase + coff] = v;
    }
  }
}

// ---------------------------------------------------------------------------
// Causal flash attention, KVBLK=64, K double-buffered with counted-vmcnt
// prefetch; V issue-early/write-late (T14); setprio on MFMA clusters (T5).
// PAIRED q-tiles: block (bh, pr) handles qt = 15-pr then qt = pr -> every
// block does exactly 34 tile-units; grid 512 = 2 blocks/CU, all resident.
// Softmax: log2 domain, defer-max (T13); l via ones-column MFMA (acc[*][8]).
// ---------------------------------------------------------------------------
__global__ __launch_bounds__(256, 2)
void attn_kernel(const unsigned short* __restrict__ Qb,
                 const unsigned short* __restrict__ Kb,
                 const unsigned short* __restrict__ Vb,
                 unsigned short* __restrict__ Ob) {
  __shared__ unsigned short lK[2][64 * 128];    // 2 x 16 KB, swizzled rows
  __shared__ unsigned short lVt[144 * 72];      // V^T + ones rows 128..143
  __shared__ unsigned short lP[4][32 * 72];     // per-wave P [32 q][64 k]

  const int tid = threadIdx.x;
  const int wave = tid >> 6, lane = tid & 63;
  const int lo = lane & 15, hi = lane >> 4;
  const int bh = blockIdx.x & 63;
  const int pr = blockIdx.x >> 6;               // 0..7 (q-tile pair index)
  const size_t base = (size_t)bh * 2048 * 128;
  const float SCL = 0.08838834764831845f * 1.4426950408889634f;
  const float THR = 11.5416f;                   // 8 * log2(e)
  const int rr = tid & 31, c0v = (tid >> 5) * 8;

  // ones rows (d=128..143, 64 cols); written once, never overwritten
#pragma unroll
  for (int x = tid; x < 1024; x += 256)
    lVt[(128 + (x >> 6)) * 72 + (x & 63)] = 0x3F80;  // bf16 1.0

#define STAGEK(KT2, BUF)                                                       \
  do {                                                                         \
    _Pragma("unroll")                                                          \
    for (int j = 0; j < 4; j++) {                                              \
      int lrow = j * 16 + wave * 4 + hi;                                       \
      int srccol = (lo * 16) ^ ((lrow & 7) << 4);                              \
      gload16(Kb + base + (size_t)((KT2) * 64 + lrow) * 128 + (srccol >> 1),   \
              &lK[BUF][(j * 16 + wave * 4) * 128]);                            \
    }                                                                          \
  } while (0)

  for (int hseq = 0; hseq < 2; ++hseq) {
    const int qt = hseq ? pr : 15 - pr;         // heavy subtile first
    const int q0 = qt * 128 + wave * 32;
    const int ktn = qt * 2 + 2;                 // 64-key tiles to causal edge
    const int qmax_w = q0 + 31;

    bf16x8 aq[2][4];
#pragma unroll
    for (int mi = 0; mi < 2; mi++)
#pragma unroll
      for (int dk = 0; dk < 4; dk++)
        aq[mi][dk] = *(const bf16x8*)&Qb[base + (size_t)(q0 + mi * 16 + lo) * 128 + dk * 32 + hi * 8];

    f32x4 acc[2][9] = {};                       // [.][8] = l (ones column)
    float mrun[2][4];
#pragma unroll
    for (int a = 0; a < 2; a++)
#pragma unroll
      for (int b = 0; b < 4; b++) mrun[a][b] = -INFINITY;

    STAGEK(0, 0);

    for (int kt = 0; kt < ktn; kt++) {
      // ---- V issue-early (4 global loads to regs; oldest in vmcnt queue) ----
      const unsigned short* vp0 = Vb + base + (size_t)(kt * 64 + 2 * rr) * 128 + c0v;
      s16x8 v00 = *(const s16x8*)vp0;
      s16x8 v01 = *(const s16x8*)(vp0 + 128);
      s16x8 v10 = *(const s16x8*)(vp0 + 64);
      s16x8 v11 = *(const s16x8*)(vp0 + 192);
      // ---- K(kt+1) prefetch; drain K(kt)+V only ----
      if (kt + 1 < ktn) { STAGEK(kt + 1, (kt + 1) & 1); VMC(8); }
      else { VMC(0); }
      BAR;

      const bool docomp = (kt * 64 <= qmax_w);
      if (docomp) {
        const unsigned short* lKc = &lK[kt & 1][0];
        f32x4 sc[2][4] = {};
        __builtin_amdgcn_s_setprio(1);
#pragma unroll
        for (int ni = 0; ni < 4; ni++)
#pragma unroll
          for (int dk = 0; dk < 4; dk++) {
            int row = ni * 16 + lo;
            int col = (dk * 32 + hi * 8) ^ ((row & 7) << 3);
            bf16x8 bk_ = *(const bf16x8*)&lKc[row * 128 + col];
            sc[0][ni] = MFMA16(aq[0][dk], bk_, sc[0][ni]);
            sc[1][ni] = MFMA16(aq[1][dk], bk_, sc[1][ni]);
          }
        __builtin_amdgcn_s_setprio(0);
        float tm[2][4];
        bool cond = true;
#pragma unroll
        for (int mi = 0; mi < 2; mi++)
#pragma unroll
          for (int i = 0; i < 4; i++) {
            int qrow = q0 + mi * 16 + hi * 4 + i;
            float mx = -INFINITY;
#pragma unroll
            for (int ni = 0; ni < 4; ni++) {
              int kc = kt * 64 + ni * 16 + lo;
              float s = sc[mi][ni][i] * SCL;
              if (kc > qrow) s = -INFINITY;
              sc[mi][ni][i] = s;
              mx = fmaxf(mx, s);
            }
            tm[mi][i] = mx;
            cond = cond && (mx <= mrun[mi][i] + THR);
          }
        if (!__all((int)cond)) {
#pragma unroll
          for (int mi = 0; mi < 2; mi++)
#pragma unroll
            for (int i = 0; i < 4; i++) {
              float mt = tm[mi][i];
              mt = fmaxf(mt, __shfl_xor(mt, 1));
              mt = fmaxf(mt, __shfl_xor(mt, 2));
              mt = fmaxf(mt, __shfl_xor(mt, 4));
              mt = fmaxf(mt, __shfl_xor(mt, 8));
              float mo = mrun[mi][i];
              float mn = fmaxf(mo, mt);
              float alpha = exp2f(mo - mn);
              mrun[mi][i] = mn;
#pragma unroll
              for (int ni = 0; ni < 9; ni++) acc[mi][ni][i] *= alpha;
            }
        }
        unsigned short* lPw = &lP[wave][0];
#pragma unroll
        for (int mi = 0; mi < 2; mi++)
#pragma unroll
          for (int i = 0; i < 4; i++) {
            float m = mrun[mi][i];
            int prow = mi * 16 + hi * 4 + i;
#pragma unroll
            for (int ni = 0; ni < 4; ni++)
              lPw[prow * 72 + ni * 16 + lo] = f2bf(exp2f(sc[mi][ni][i] - m));
          }
      }

      // ---- V write-late (compiler-inserted waits cover the V regs) ----
#pragma unroll
      for (int j = 0; j < 8; j++) {
        *(ushort2*)&lVt[(c0v + j) * 72 + 2 * rr] =
            make_ushort2((unsigned short)v00[j], (unsigned short)v01[j]);
        *(ushort2*)&lVt[(c0v + 64 + j) * 72 + 2 * rr] =
            make_ushort2((unsigned short)v10[j], (unsigned short)v11[j]);
      }
      asm volatile("s_waitcnt lgkmcnt(0)" ::: "memory");
      BAR;

      if (docomp) {
        unsigned short* lPw = &lP[wave][0];
        bf16x8 ap[2][2];
#pragma unroll
        for (int mi = 0; mi < 2; mi++)
#pragma unroll
          for (int k2 = 0; k2 < 2; k2++)
            ap[mi][k2] = *(const bf16x8*)&lPw[(mi * 16 + lo) * 72 + k2 * 32 + hi * 8];
        __builtin_amdgcn_s_setprio(1);
#pragma unroll
        for (int ni = 0; ni < 9; ni++)
#pragma unroll
          for (int k2 = 0; k2 < 2; k2++) {
            bf16x8 bv_ = *(const bf16x8*)&lVt[(ni * 16 + lo) * 72 + k2 * 32 + hi * 8];
            acc[0][ni] = MFMA16(ap[0][k2], bv_, acc[0][ni]);
            acc[1][ni] = MFMA16(ap[1][k2], bv_, acc[1][ni]);
          }
        __builtin_amdgcn_s_setprio(0);
      }
    }

    // ---- epilogue: O[b, s, h*128+d] = acc / l, l = acc[mi][8][i] ----
    const int b = bh >> 4, hh = bh & 15;
#pragma unroll
    for (int mi = 0; mi < 2; mi++)
#pragma unroll
      for (int i = 0; i < 4; i++) {
        float inv = 1.0f / acc[mi][8][i];
        int s = q0 + mi * 16 + hi * 4 + i;
        size_t rowbase = ((size_t)b * 2048 + s) * 2048 + hh * 128 + lo;
#pragma unroll
        for (int ni = 0; ni < 8; ni++)
          Ob[rowbase + ni * 16] = f2bf(acc[mi][ni][i] * inv);
      }
  }
}

// ---------------------------------------------------------------------------
extern "C" void kernel_launch(void* const* d_in, const int* in_sizes, int n_in,
                              void* d_out, int out_size, void* d_ws, size_t ws_size,
                              hipStream_t stream) {
  const float* h  = (const float*)d_in[0];
  const float* Wq = (const float*)d_in[1];
  const float* bq = (const float*)d_in[2];
  const float* Wk = (const float*)d_in[3];
  const float* bk = (const float*)d_in[4];
  const float* Wv = (const float*)d_in[5];
  const float* bv = (const float*)d_in[6];
  const float* Wo = (const float*)d_in[7];
  const float* bo = (const float*)d_in[8];
  float* out = (float*)d_out;

  char* ws = (char*)d_ws;
  unsigned short* h_bf  = (unsigned short*)(ws + 0);            // 32 MiB
  unsigned short* Qb    = (unsigned short*)(ws + 33554432);     // 32 MiB
  unsigned short* Kb    = (unsigned short*)(ws + 67108864);     // 32 MiB
  unsigned short* Vb    = (unsigned short*)(ws + 100663296);    // 32 MiB
  unsigned short* Wqkv  = (unsigned short*)(ws + 134217728);    // 24 MiB
  unsigned short* Wo_bf = (unsigned short*)(ws + 159383552);    // 8 MiB
  unsigned short* Ob    = h_bf;                                 // reuse after QKV GEMM

  // fp32 -> bf16 conversions (h + all weights, one launch)
  cvt_all<<<16384, 256, 0, stream>>>(h, Wq, Wk, Wv, Wo, h_bf, Wqkv, Wo_bf);

  // QKV projection (M=8192, N=6144, K=2048), 32x24 blocks of 256x256
  gemm_qkv<<<dim3(768), dim3(512), 0, stream>>>(h_bf, Wqkv, bq, bk, bv, Qb, Kb, Vb);

  // causal attention (64 bh x 8 q-tile pairs)
  attn_kernel<<<dim3(512), dim3(256), 0, stream>>>(Qb, Kb, Vb, Ob);

  // output projection (M=8192, N=2048, K=2048), 32x8 blocks, fp32 out
  gemm_out<<<dim3(256), dim3(512), 0, stream>>>(Ob, Wo_bf, bo, out);
}